// Round 8
// baseline (566.833 us; speedup 1.0000x reference)
//
#include <hip/hip_runtime.h>

#define N_NODES 100000
#define N_EDGES 3200000
#define DIM 256

typedef _Float16 half_t;
typedef __attribute__((ext_vector_type(4))) _Float16 half4;
typedef __attribute__((ext_vector_type(8))) _Float16 half8;
typedef __attribute__((ext_vector_type(4))) float floatx4;

// ---------------------------------------------------------------------------
// Geometry
// ---------------------------------------------------------------------------
#define BM 128
#define BK 32
#define LDK 40
#define GEMM_BLOCKS 782                  // ceil(100000 / 128)

#define NBUCK 500                        // buckets of RPB rows: 500*200 = 100000
#define RPB 200
#define CAPG 8192                        // tmp slots/bucket (mean 6400, +22 sigma)
#define STRIDE_I2 25600                  // 204800 B / 8: bucket b tmp at its OWN
                                         // out window -> no cross-block race
#define EPB 16384                        // edges per scatter block
#define NEB 196                          // ceil(3.2M / 16384)

// ---------------------------------------------------------------------------
// W cast+transpose: wT[n][k] = (f16) w[k][n].
// ---------------------------------------------------------------------------
__global__ __launch_bounds__(256) void castw_kernel(const float* __restrict__ w,
                                                    half_t* __restrict__ wT) {
    __shared__ float tile[32][33];
    int bk = blockIdx.x * 32;
    int bn = blockIdx.y * 32;
    int tx = threadIdx.x & 31, ty = threadIdx.x >> 5;
#pragma unroll
    for (int i = 0; i < 4; i++)
        tile[ty + i * 8][tx] = w[(size_t)(bk + ty + i * 8) * DIM + bn + tx];
    __syncthreads();
#pragma unroll
    for (int i = 0; i < 4; i++)
        wT[(size_t)(bn + ty + i * 8) * DIM + bk + tx] = (half_t)tile[tx][ty + i * 8];
}

// ---------------------------------------------------------------------------
// Fused kernel 1: blocks [0, GEMM_BLOCKS) do the MFMA GEMM (support = x @ W,
// f16 out, 128x256 tile, 8 waves); blocks [GEMM_BLOCKS, +NEB) scatter edges
// into per-bucket tmp regions (LDS-aggregated cursors, chunk reservation).
// Independent producers -> horizontal fusion overlaps MFMA with scatter BW.
// ---------------------------------------------------------------------------
__global__ __launch_bounds__(512) void gemm_scatter_kernel(
        const float* __restrict__ A, const half_t* __restrict__ BT,
        half_t* __restrict__ C,
        const int* __restrict__ erow, const int* __restrict__ ecol,
        const float* __restrict__ eval, int* __restrict__ bcursor,
        int2* __restrict__ tmp) {
    __shared__ __align__(16) char smem[30720];
    const int tid = threadIdx.x;

    if (blockIdx.x < GEMM_BLOCKS) {
        // ================= GEMM role =================
        half_t (*As)[LDK] = (half_t (*)[LDK])smem;            // 128 x 40 f16
        half_t (*Bs)[LDK] = (half_t (*)[LDK])(smem + 10240);  // 256 x 40 f16

        const int wid = tid >> 6, lane = tid & 63;
        const int wm = wid & 1, wn = wid >> 1;   // 2 x 4 wave grid
        const int row0 = blockIdx.x * BM;
        const int lr = lane & 15;
        const int quad = lane >> 4;

        floatx4 acc[4][4] = {};

        const int ar = tid >> 2;
        const int ac = (tid & 3) * 8;
        const bool avalid = (row0 + ar) < N_NODES;
        const float* aptr = A + (size_t)(row0 + ar) * DIM + ac;

        for (int k0 = 0; k0 < DIM; k0 += BK) {
            {   // stage A (fp32 -> f16): 128x32
                const float4* src = (const float4*)(aptr + k0);
                half_t* dst = &As[ar][ac];
#pragma unroll
                for (int i = 0; i < 2; i++) {
                    float4 v = avalid ? src[i] : make_float4(0.f, 0.f, 0.f, 0.f);
                    half4 h;
                    h.x = (half_t)v.x; h.y = (half_t)v.y;
                    h.z = (half_t)v.z; h.w = (half_t)v.w;
                    ((half4*)dst)[i] = h;
                }
            }
            {   // stage B: 256 n-rows x 32 k
#pragma unroll
                for (int i = 0; i < 2; i++) {
                    int ch = tid + i * 512;
                    int r = ch >> 2, cb = (ch & 3) * 8;
                    half8 v = *(const half8*)(BT + (size_t)r * DIM + k0 + cb);
                    *(half8*)&Bs[r][cb] = v;
                }
            }
            __syncthreads();

            half8 a[4], b[4];
#pragma unroll
            for (int i = 0; i < 4; i++)
                a[i] = *(const half8*)&As[wm * 64 + i * 16 + lr][quad * 8];
#pragma unroll
            for (int j = 0; j < 4; j++)
                b[j] = *(const half8*)&Bs[wn * 64 + j * 16 + lr][quad * 8];
#pragma unroll
            for (int i = 0; i < 4; i++)
#pragma unroll
                for (int j = 0; j < 4; j++)
                    acc[i][j] = __builtin_amdgcn_mfma_f32_16x16x32_f16(
                        a[i], b[j], acc[i][j], 0, 0, 0);
            __syncthreads();
        }

#pragma unroll
        for (int i = 0; i < 4; i++) {
#pragma unroll
            for (int j = 0; j < 4; j++) {
                int gc = wn * 64 + j * 16 + lr;
                int grb = row0 + wm * 64 + i * 16 + quad * 4;
#pragma unroll
                for (int r = 0; r < 4; r++) {
                    int gr = grb + r;
                    if (gr < N_NODES) C[(size_t)gr * DIM + gc] = (half_t)acc[i][j][r];
                }
            }
        }
    } else {
        // ================= scatter role =================
        int* lh = (int*)smem;            // [NBUCK] hist -> rank cursor
        int* lbase = lh + NBUCK;         // [NBUCK] reserved global base (int2 idx)
        const int sb = blockIdx.x - GEMM_BLOCKS;

        for (int b = tid; b < NBUCK; b += 512) lh[b] = 0;
        __syncthreads();

        int base4 = sb * (EPB / 4);
        // phase 1: local bucket histogram
#pragma unroll
        for (int i = 0; i < 8; i++) {
            int idx4 = base4 + i * 512 + tid;
            if (idx4 < N_EDGES / 4) {
                int4 r4 = ((const int4*)erow)[idx4];
                atomicAdd(&lh[(unsigned)r4.x / RPB], 1);
                atomicAdd(&lh[(unsigned)r4.y / RPB], 1);
                atomicAdd(&lh[(unsigned)r4.z / RPB], 1);
                atomicAdd(&lh[(unsigned)r4.w / RPB], 1);
            }
        }
        __syncthreads();
        // reserve contiguous chunks inside each bucket's fixed region
        for (int b = tid; b < NBUCK; b += 512) {
            int c = lh[b];
            int st = 0;
            if (c) {
                st = atomicAdd(&bcursor[b * 16], c);
                if (st > CAPG - c) st = CAPG - c;   // astronomically-rare clamp
                if (st < 0) st = 0;
            }
            lbase[b] = b * STRIDE_I2 + st;
            lh[b] = 0;                              // becomes rank cursor
        }
        __syncthreads();

        // phase 2: re-read (L2-warm) & scatter.
        // record: .x = (rowlocal << 17) | col  (col < 2^17, rowlocal < 256)
#define SCAT(R, C, V)                                                      \
        {                                                                  \
            unsigned _r = (unsigned)(R); int _c = (C);                     \
            int _b = _r / RPB;                                             \
            int _rl = _r - _b * RPB;                                       \
            int _rank = atomicAdd(&lh[_b], 1);                             \
            tmp[lbase[_b] + _rank] =                                       \
                make_int2((_rl << 17) | _c, __float_as_int(V));            \
        }
#pragma unroll
        for (int i = 0; i < 8; i++) {
            int idx4 = base4 + i * 512 + tid;
            if (idx4 < N_EDGES / 4) {
                int4 r4 = ((const int4*)erow)[idx4];
                int4 c4 = ((const int4*)ecol)[idx4];
                float4 v4 = ((const float4*)eval)[idx4];
                SCAT(r4.x, c4.x, v4.x);
                SCAT(r4.y, c4.y, v4.y);
                SCAT(r4.z, c4.z, v4.z);
                SCAT(r4.w, c4.w, v4.w);
            }
        }
#undef SCAT
    }
}

// ---------------------------------------------------------------------------
// Fused kernel 2: one block per bucket (500 blocks x 512 thr, 2 blocks/CU).
// Phase A: read bucket's tmp edges, LDS hist+scan over its 200 rows, scatter
//          edges into an LDS CSR (int2 ledge[8192], 64 KB).
// Phase B: round-3 spmm gather loop, edges served from LDS, full D.
// tmp bucket b occupies the FIRST 64 KB of block b's own out window, and is
// fully drained to LDS before any out write -> no cross-block race.
// ---------------------------------------------------------------------------
__global__ __launch_bounds__(512, 4) void csr_spmm_kernel(
        const half_t* __restrict__ support, const int* __restrict__ bcnt,
        const int2* __restrict__ tmp, float* __restrict__ out) {
    __shared__ int lh[256];
    __shared__ int s[256];
    __shared__ int roff[257];
    __shared__ __align__(16) int2 ledge[CAPG];

    const int b = blockIdx.x;
    const int t = threadIdx.x;
    int cnt = bcnt[b * 16];
    if (cnt > CAPG) cnt = CAPG;
    const int2* src = tmp + (size_t)b * STRIDE_I2;
    const int row0 = b * RPB;

    // ---- Phase A: LDS CSR build ----
    if (t < 256) lh[t] = 0;
    __syncthreads();
    for (int e = t; e < cnt; e += 512)
        atomicAdd(&lh[src[e].x >> 17], 1);
    __syncthreads();

    if (t < 256) s[t] = lh[t];
    __syncthreads();
    for (int off = 1; off < 256; off <<= 1) {
        int u = 0;
        if (t < 256 && t >= off) u = s[t - off];
        __syncthreads();
        if (t < 256) s[t] += u;
        __syncthreads();
    }
    if (t < 256) {
        int ex = s[t] - lh[t];
        roff[t] = ex;     // exclusive prefix; bins >= RPB are 0 -> roff[RPB]=cnt
        lh[t] = ex;       // rank cursor
    }
    if (t == 0) roff[256] = cnt;
    __syncthreads();

    for (int e = t; e < cnt; e += 512) {
        int2 q = src[e];
        int lr = q.x >> 17;
        int rank = atomicAdd(&lh[lr], 1);
        ledge[rank] = make_int2(q.x & 0x1FFFF, q.y);
    }
    __syncthreads();

    // ---- Phase B: gather spmm (full D), 8 waves x strided rows ----
    const int wid = t >> 6, lane = t & 63;
    const int h = lane >> 5;   // half-wave: which edge of a pair
    const int j = lane & 31;   // 16 B chunk within the 512 B support row

    for (int r = wid; r < RPB; r += 8) {
        int row = row0 + r;
        int beg = roff[r];
        int end = roff[r + 1];

        float acc[8] = {0.f, 0.f, 0.f, 0.f, 0.f, 0.f, 0.f, 0.f};
        int e = beg;

        // parity peel: make e even so int4 LDS edge reads are 16B-aligned
        if ((e & 1) && e < end) {
            int2 q = ledge[e];
            half8 sv = *(const half8*)(support + (size_t)q.x * DIM + j * 8);
            float v = (h == 0) ? __int_as_float(q.y) : 0.f;
#pragma unroll
            for (int d = 0; d < 8; d++) acc[d] += v * (float)sv[d];
            e++;
        }

        for (; e + 15 < end; e += 16) {
            int4 pa = *(const int4*)&ledge[e + 2 * h];
            int4 pb = *(const int4*)&ledge[e + 4 + 2 * h];
            int4 pc = *(const int4*)&ledge[e + 8 + 2 * h];
            int4 pd = *(const int4*)&ledge[e + 12 + 2 * h];
            half8 s0 = *(const half8*)(support + (size_t)pa.x * DIM + j * 8);
            half8 s1 = *(const half8*)(support + (size_t)pa.z * DIM + j * 8);
            half8 s2 = *(const half8*)(support + (size_t)pb.x * DIM + j * 8);
            half8 s3 = *(const half8*)(support + (size_t)pb.z * DIM + j * 8);
            half8 s4 = *(const half8*)(support + (size_t)pc.x * DIM + j * 8);
            half8 s5 = *(const half8*)(support + (size_t)pc.z * DIM + j * 8);
            half8 s6 = *(const half8*)(support + (size_t)pd.x * DIM + j * 8);
            half8 s7 = *(const half8*)(support + (size_t)pd.z * DIM + j * 8);
            float v0 = __int_as_float(pa.y), v1 = __int_as_float(pa.w);
            float v2 = __int_as_float(pb.y), v3 = __int_as_float(pb.w);
            float v4 = __int_as_float(pc.y), v5 = __int_as_float(pc.w);
            float v6 = __int_as_float(pd.y), v7 = __int_as_float(pd.w);
#pragma unroll
            for (int d = 0; d < 8; d++)
                acc[d] += v0 * (float)s0[d] + v1 * (float)s1[d]
                        + v2 * (float)s2[d] + v3 * (float)s3[d]
                        + v4 * (float)s4[d] + v5 * (float)s5[d]
                        + v6 * (float)s6[d] + v7 * (float)s7[d];
        }
        for (; e + 1 < end; e += 2) {
            int2 q = ledge[e + h];
            half8 sv = *(const half8*)(support + (size_t)q.x * DIM + j * 8);
            float v = __int_as_float(q.y);
#pragma unroll
            for (int d = 0; d < 8; d++) acc[d] += v * (float)sv[d];
        }
        if (e < end) {   // odd tail: both halves load it; half 1 contributes 0
            int2 q = ledge[e];
            half8 sv = *(const half8*)(support + (size_t)q.x * DIM + j * 8);
            float v = (h == 0) ? __int_as_float(q.y) : 0.f;
#pragma unroll
            for (int d = 0; d < 8; d++) acc[d] += v * (float)sv[d];
        }

        // cross-half combine: lane (h, j) keeps dims j*8 + h*4 .. +4
        float r0, r1, r2, r3, g0, g1, g2, g3;
        if (h == 0) {
            r0 = acc[0]; r1 = acc[1]; r2 = acc[2]; r3 = acc[3];
            g0 = acc[4]; g1 = acc[5]; g2 = acc[6]; g3 = acc[7];
        } else {
            r0 = acc[4]; r1 = acc[5]; r2 = acc[6]; r3 = acc[7];
            g0 = acc[0]; g1 = acc[1]; g2 = acc[2]; g3 = acc[3];
        }
        r0 += __shfl_xor(g0, 32, 64);
        r1 += __shfl_xor(g1, 32, 64);
        r2 += __shfl_xor(g2, 32, 64);
        r3 += __shfl_xor(g3, 32, 64);

        *(float4*)(out + (size_t)row * DIM + j * 8 + h * 4) =
            make_float4(r0, r1, r2, r3);
    }
}

extern "C" void kernel_launch(void* const* d_in, const int* in_sizes, int n_in,
                              void* d_out, int out_size, void* d_ws, size_t ws_size,
                              hipStream_t stream) {
    const float* x    = (const float*)d_in[0];
    const float* w    = (const float*)d_in[1];
    const int*   erow = (const int*)d_in[2];
    const int*   ecol = (const int*)d_in[3];
    const float* eval = (const float*)d_in[4];
    float* out = (float*)d_out;

    // workspace: support 51.2 MB | wT 131 KB | bcnt 32 KB  (total 51.37 MB)
    char* ws = (char*)d_ws;
    half_t* support = (half_t*)ws;                 // 51,200,000 B
    half_t* wT      = (half_t*)(ws + 51200000);    //    131,072 B
    int*    bcnt    = (int*)(ws + 51331072);       // 500*64 B stride-16 cursors
    // bucket-major tmp edges in d_out: bucket b at int2-offset b*25600
    // (byte b*204800 = block b's own out window; max end 102,359,040+65,536
    //  <= 102,400,000). Drained to LDS before that block writes out.
    int2*   tmp     = (int2*)d_out;

    hipMemsetAsync(bcnt, 0, NBUCK * 16 * sizeof(int), stream);

    castw_kernel<<<dim3(8, 8), 256, 0, stream>>>(w, wT);

    gemm_scatter_kernel<<<GEMM_BLOCKS + NEB, 512, 0, stream>>>(
        x, wT, support, erow, ecol, eval, bcnt, tmp);

    csr_spmm_kernel<<<NBUCK, 512, 0, stream>>>(support, bcnt, tmp, out);
}